// Round 5
// baseline (588.904 us; speedup 1.0000x reference)
//
#include <hip/hip_runtime.h>
#include <stdint.h>

// GCN: out = Dinv (A+I) Dinv (X W) + b, two layers, relu between.
// N=100000, E=1600000, K=128, C1=128, C2=64. All float32 (edge_index int32).
// R5: csr_fill via atomicExch (atomics write 4B exact; plain scattered stores cost a
//     64B line each -> 105MB writeback for 6.4MB logical, measured R4) +
//     wave-broadcast gather (1 coalesced csr load per 64 edges, __shfl distribute).

static constexpr int KD = 128;

// ---------------- degree histogram (int) ----------------
__global__ __launch_bounds__(256) void deg_count(const int* __restrict__ dst,
                                                 int* __restrict__ deg, int e) {
    int i = blockIdx.x * 256 + threadIdx.x;
    if (i < e) atomicAdd(&deg[dst[i]], 1);
}

// ---------------- exclusive scan (3 passes), 1024 elems/block ----------------
__global__ __launch_bounds__(256) void scan1(const int* __restrict__ deg,
        int* __restrict__ roff, int* __restrict__ bsum, int n) {
    __shared__ int wsum[4];
    const int t = threadIdx.x;
    const int base = blockIdx.x * 1024 + t * 4;
    int d0 = 0, d1 = 0, d2 = 0, d3 = 0;
    if (base + 0 < n) d0 = deg[base + 0];
    if (base + 1 < n) d1 = deg[base + 1];
    if (base + 2 < n) d2 = deg[base + 2];
    if (base + 3 < n) d3 = deg[base + 3];
    int tsum = d0 + d1 + d2 + d3;
    int lane = t & 63, wv = t >> 6;
    int v = tsum;
    for (int off = 1; off < 64; off <<= 1) {
        int u = __shfl_up(v, off, 64);
        if (lane >= off) v += u;
    }
    if (lane == 63) wsum[wv] = v;
    __syncthreads();
    int woff = 0;
    for (int i = 0; i < wv; ++i) woff += wsum[i];
    int excl = v - tsum + woff;
    if (base + 0 < n) roff[base + 0] = excl;
    if (base + 1 < n) roff[base + 1] = excl + d0;
    if (base + 2 < n) roff[base + 2] = excl + d0 + d1;
    if (base + 3 < n) roff[base + 3] = excl + d0 + d1 + d2;
    if (t == 255) bsum[blockIdx.x] = excl + tsum;
}

__global__ __launch_bounds__(256) void scan2(int* __restrict__ bsum, int nb) {
    __shared__ int buf[256];
    int t = threadIdx.x;
    if (nb <= 256) {
        int v = (t < nb) ? bsum[t] : 0;
        buf[t] = v;
        __syncthreads();
        for (int off = 1; off < 256; off <<= 1) {
            int u = (t >= off) ? buf[t - off] : 0;
            __syncthreads();
            buf[t] += u;
            __syncthreads();
        }
        if (t < nb) bsum[t] = buf[t] - v;   // exclusive
    } else if (t == 0) {
        int run = 0;
        for (int i = 0; i < nb; ++i) { int v = bsum[i]; bsum[i] = run; run += v; }
    }
}

__global__ __launch_bounds__(256) void scan3(int* __restrict__ roff,
        const int* __restrict__ bsum, int* __restrict__ cursor_deg,
        float* __restrict__ dinv, int n, int e_total) {
    int i = blockIdx.x * 256 + threadIdx.x;
    if (i >= n) return;
    int d = cursor_deg[i];
    dinv[i] = rsqrtf((float)(d + 1));
    int v = roff[i] + bsum[i >> 10];
    roff[i] = v;
    cursor_deg[i] = v;
    if (i == 0) roff[n] = e_total;
}

// ---------------- CSR fill (atomicExch: 4B exact write, no line writeback) -----------
__global__ __launch_bounds__(256) void csr_fill(const int* __restrict__ src,
        const int* __restrict__ dst, int* __restrict__ cursor,
        int* __restrict__ csr, int e) {
    int i = blockIdx.x * 256 + threadIdx.x;
    if (i >= e) return;
    int d = dst[i];
    int s = src[i];
    int slot = atomicAdd(&cursor[d], 1);
    atomicExch(&csr[slot], s);
}

// ---------------- register-tiled GEMM: out[i][c] = dinv[i] * sum_k x[i][k]*W[k][c] ----
template<int C, int KSTAGE>
__global__ __launch_bounds__(256) void gemm_tiled(const float* __restrict__ x,
        const float* __restrict__ W, const float* __restrict__ dinv,
        float* __restrict__ out, int n)
{
    constexpr int CT = C / 16;                  // 8 for C=128, 4 for C=64
    __shared__ __align__(16) float lws[KSTAGE * C];
    __shared__ float lx[64][KD + 2];
    const int t = threadIdx.x;
    const int row0 = blockIdx.x * 64;

    for (int i = t; i < 64 * (KD / 4); i += 256) {
        int r = i >> 5, k4 = (i & 31) * 4;
        int row = row0 + r;
        float4 v = make_float4(0.f, 0.f, 0.f, 0.f);
        if (row < n) v = *reinterpret_cast<const float4*>(&x[(size_t)row * KD + k4]);
        lx[r][k4 + 0] = v.x; lx[r][k4 + 1] = v.y;
        lx[r][k4 + 2] = v.z; lx[r][k4 + 3] = v.w;
    }

    const int ty = t >> 4;
    const int tx = t & 15;
    const int r0 = ty * 4;
    const int cb = tx * CT;

    float acc[4][CT];
#pragma unroll
    for (int i = 0; i < 4; ++i)
#pragma unroll
        for (int j = 0; j < CT; ++j) acc[i][j] = 0.0f;

    for (int kt = 0; kt < KD / KSTAGE; ++kt) {
        __syncthreads();
        {
            const float4* W4 = reinterpret_cast<const float4*>(W + (size_t)kt * KSTAGE * C);
            float4* l4 = reinterpret_cast<float4*>(lws);
            for (int i = t; i < KSTAGE * C / 4; i += 256) l4[i] = W4[i];
        }
        __syncthreads();
        const int kb = kt * KSTAGE;
#pragma unroll 4
        for (int k = 0; k < KSTAGE; k += 2) {
            float2 xv[4];
#pragma unroll
            for (int i = 0; i < 4; ++i)
                xv[i] = *reinterpret_cast<const float2*>(&lx[r0 + i][kb + k]);
#pragma unroll
            for (int kk = 0; kk < 2; ++kk) {
#pragma unroll
                for (int j = 0; j < CT / 4; ++j) {
                    float4 wv = *reinterpret_cast<const float4*>(&lws[(k + kk) * C + cb + 4 * j]);
#pragma unroll
                    for (int i = 0; i < 4; ++i) {
                        float xs = kk ? xv[i].y : xv[i].x;
                        acc[i][4*j+0] += xs * wv.x;
                        acc[i][4*j+1] += xs * wv.y;
                        acc[i][4*j+2] += xs * wv.z;
                        acc[i][4*j+3] += xs * wv.w;
                    }
                }
            }
        }
    }

#pragma unroll
    for (int i = 0; i < 4; ++i) {
        int row = row0 + r0 + i;
        if (row < n) {
            float s = dinv[row];
#pragma unroll
            for (int j = 0; j < CT / 4; ++j) {
                float4 v = make_float4(acc[i][4*j+0]*s, acc[i][4*j+1]*s,
                                       acc[i][4*j+2]*s, acc[i][4*j+3]*s);
                *reinterpret_cast<float4*>(&out[(size_t)row * C + cb + 4*j]) = v;
            }
        }
    }
}

// ---------------- gather-aggregate: one wave per node ----------------
// Indices loaded once per 64 edges (lane-coalesced), distributed via __shfl.
template<bool RELU>
__global__ __launch_bounds__(256) void gather128(const float* __restrict__ h,
        const int* __restrict__ roff, const int* __restrict__ csr,
        const float* __restrict__ dinv, const float* __restrict__ b,
        float* __restrict__ out, int n)
{
    int wid = (blockIdx.x * 256 + threadIdx.x) >> 6;
    int lane = threadIdx.x & 63;
    if (wid >= n) return;
    const float2* hl = (const float2*)h + lane;
    float2 acc = hl[(size_t)wid * 64];          // self loop
    float2 a1 = make_float2(0.f, 0.f);
    int e0 = roff[wid], e1 = roff[wid + 1];
    for (int base = e0; base < e1; base += 64) {
        int m = e1 - base; if (m > 64) m = 64;
        int idx = (lane < m) ? csr[base + lane] : 0;
        int j = 0;
        for (; j + 8 <= m; j += 8) {
            int u0 = __shfl(idx, j+0), u1 = __shfl(idx, j+1);
            int u2 = __shfl(idx, j+2), u3 = __shfl(idx, j+3);
            int u4 = __shfl(idx, j+4), u5 = __shfl(idx, j+5);
            int u6 = __shfl(idx, j+6), u7 = __shfl(idx, j+7);
            float2 t0 = hl[(size_t)u0 * 64];
            float2 t1 = hl[(size_t)u1 * 64];
            float2 t2 = hl[(size_t)u2 * 64];
            float2 t3 = hl[(size_t)u3 * 64];
            float2 t4 = hl[(size_t)u4 * 64];
            float2 t5 = hl[(size_t)u5 * 64];
            float2 t6 = hl[(size_t)u6 * 64];
            float2 t7 = hl[(size_t)u7 * 64];
            acc.x += t0.x + t1.x; acc.y += t0.y + t1.y;
            a1.x  += t2.x + t3.x; a1.y  += t2.y + t3.y;
            acc.x += t4.x + t5.x; acc.y += t4.y + t5.y;
            a1.x  += t6.x + t7.x; a1.y  += t6.y + t7.y;
        }
        for (; j < m; ++j) {
            int u = __shfl(idx, j);
            float2 t = hl[(size_t)u * 64];
            acc.x += t.x; acc.y += t.y;
        }
    }
    acc.x += a1.x; acc.y += a1.y;
    float s = dinv[wid];
    float2 bb = ((const float2*)b)[lane];
    acc.x = s * acc.x + bb.x;
    acc.y = s * acc.y + bb.y;
    if (RELU) { acc.x = fmaxf(acc.x, 0.f); acc.y = fmaxf(acc.y, 0.f); }
    ((float2*)out)[(size_t)wid * 64 + lane] = acc;
}

template<bool RELU>
__global__ __launch_bounds__(256) void gather64(const float* __restrict__ h,
        const int* __restrict__ roff, const int* __restrict__ csr,
        const float* __restrict__ dinv, const float* __restrict__ b,
        float* __restrict__ out, int n)
{
    int wid = (blockIdx.x * 256 + threadIdx.x) >> 6;
    int lane = threadIdx.x & 63;
    if (wid >= n) return;
    const float* hl = h + lane;
    float acc = hl[(size_t)wid * 64];           // self loop
    float a1 = 0.f;
    int e0 = roff[wid], e1 = roff[wid + 1];
    for (int base = e0; base < e1; base += 64) {
        int m = e1 - base; if (m > 64) m = 64;
        int idx = (lane < m) ? csr[base + lane] : 0;
        int j = 0;
        for (; j + 8 <= m; j += 8) {
            int u0 = __shfl(idx, j+0), u1 = __shfl(idx, j+1);
            int u2 = __shfl(idx, j+2), u3 = __shfl(idx, j+3);
            int u4 = __shfl(idx, j+4), u5 = __shfl(idx, j+5);
            int u6 = __shfl(idx, j+6), u7 = __shfl(idx, j+7);
            float t0 = hl[(size_t)u0 * 64];
            float t1 = hl[(size_t)u1 * 64];
            float t2 = hl[(size_t)u2 * 64];
            float t3 = hl[(size_t)u3 * 64];
            float t4 = hl[(size_t)u4 * 64];
            float t5 = hl[(size_t)u5 * 64];
            float t6 = hl[(size_t)u6 * 64];
            float t7 = hl[(size_t)u7 * 64];
            acc += t0 + t1; a1 += t2 + t3;
            acc += t4 + t5; a1 += t6 + t7;
        }
        for (; j < m; ++j) {
            int u = __shfl(idx, j);
            acc += hl[(size_t)u * 64];
        }
    }
    acc += a1;
    float v = dinv[wid] * acc + b[lane];
    if (RELU) v = fmaxf(v, 0.f);
    out[(size_t)wid * 64 + lane] = v;
}

extern "C" void kernel_launch(void* const* d_in, const int* in_sizes, int n_in,
                              void* d_out, int out_size, void* d_ws, size_t ws_size,
                              hipStream_t stream)
{
    const int* ei = (const int*)d_in[0];
    const int E = in_sizes[0] / 2;
    const float* emb = (const float*)d_in[1];
    const int N = in_sizes[1] / KD;
    const float* W1 = (const float*)d_in[2];
    const float* b1 = (const float*)d_in[3];
    const float* W2 = (const float*)d_in[4];
    const float* b2 = (const float*)d_in[5];
    const int* src = ei;        // edge_index[0]
    const int* dst = ei + E;    // edge_index[1]

    // ---- workspace layout ----
    char* p = (char*)d_ws;
    auto alloc = [&](size_t bytes) { char* q = p; p += (bytes + 255) & ~(size_t)255; return q; };
    float* h1     = (float*)alloc((size_t)N * 128 * sizeof(float)); // gemm1 out; reused as h2 [N*64]
    float* x2     = (float*)alloc((size_t)N * 128 * sizeof(float)); // layer-1 activations
    int*   csr    = (int*)  alloc((size_t)E * sizeof(int));
    int*   roff   = (int*)  alloc((size_t)(N + 1) * sizeof(int));
    int*   deg    = (int*)  alloc((size_t)N * sizeof(int));         // reused as fill cursor
    int*   bsum   = (int*)  alloc(1024 * sizeof(int));
    float* dinv   = (float*)alloc((size_t)N * sizeof(float));
    float* h2     = h1;

    const int nb = (N + 1023) / 1024;

    // ---- CSR build ----
    hipMemsetAsync(deg, 0, (size_t)N * sizeof(int), stream);
    deg_count<<<(E + 255) / 256, 256, 0, stream>>>(dst, deg, E);
    scan1<<<nb, 256, 0, stream>>>(deg, roff, bsum, N);
    scan2<<<1, 256, 0, stream>>>(bsum, nb);
    scan3<<<(N + 255) / 256, 256, 0, stream>>>(roff, bsum, deg, dinv, N, E);
    csr_fill<<<(E + 255) / 256, 256, 0, stream>>>(src, dst, deg, csr, E);

    // ---- layer 1 ----
    gemm_tiled<128, 32><<<(N + 63) / 64, 256, 0, stream>>>(emb, W1, dinv, h1, N);
    gather128<true><<<(N + 3) / 4, 256, 0, stream>>>(h1, roff, csr, dinv, b1, x2, N);

    // ---- layer 2 ----
    gemm_tiled<64, 64><<<(N + 63) / 64, 256, 0, stream>>>(x2, W2, dinv, h2, N);
    gather64<false><<<(N + 3) / 4, 256, 0, stream>>>(h2, roff, csr, dinv, b2, (float*)d_out, N);
}

// Round 6
// 458.272 us; speedup vs baseline: 1.2851x; 1.2851x over previous
//
#include <hip/hip_runtime.h>
#include <stdint.h>

// GCN: out = Dinv (A+I) Dinv (X W) + b, two layers, relu between.
// N=100000, E=1600000, K=128, C1=128, C2=64. All float32 (edge_index int32).
// R6: bucketed CSR build. R4/R5 measured: random 4B scatter (store OR atomic) costs a
//     64B line of L2->mem traffic (csr_fill: 100MB for 6.4MB logical, ~150us).
//     Fix = locality: multisplit edges into 1024-node buckets (coalesced runs), then
//     one block per bucket builds deg/roff/dinv/csr with LDS counters and block-local
//     scattered stores (lines fill before eviction). Kills deg_count + N-wide scan too.

static constexpr int KD = 128;
static constexpr int BSH = 10;                 // nodes per bucket = 1024
static constexpr int MAXB = 256;               // max buckets supported
static constexpr int CHUNK = 8192;             // edges per multisplit block

// ---------------- pass 0: bucket histogram ----------------
__global__ __launch_bounds__(256) void bucket_count(const int* __restrict__ dst,
        int* __restrict__ bcnt, int e, int nbuck) {
    __shared__ int cnt[MAXB];
    const int t = threadIdx.x;
    for (int i = t; i < nbuck; i += 256) cnt[i] = 0;
    __syncthreads();
    int stride = gridDim.x * 256;
    for (int i = blockIdx.x * 256 + t; i < e; i += stride)
        atomicAdd(&cnt[dst[i] >> BSH], 1);
    __syncthreads();
    for (int i = t; i < nbuck; i += 256)
        if (cnt[i]) atomicAdd(&bcnt[i], cnt[i]);
}

// ---------------- scan buckets (1 block) ----------------
__global__ __launch_bounds__(256) void bucket_scan(const int* __restrict__ bcnt,
        int* __restrict__ bbase, int* __restrict__ bcur, int nbuck, int e) {
    __shared__ int buf[256];
    const int t = threadIdx.x;
    int v = (t < nbuck) ? bcnt[t] : 0;
    buf[t] = v;
    __syncthreads();
    for (int off = 1; off < 256; off <<= 1) {
        int u = (t >= off) ? buf[t - off] : 0;
        __syncthreads();
        buf[t] += u;
        __syncthreads();
    }
    int excl = buf[t] - v;
    if (t < nbuck) { bbase[t] = excl; bcur[t] = excl; }
    if (t == nbuck - 1 || (t == 255 && nbuck > 256)) bbase[nbuck] = e;
    if (t == 0 && nbuck <= 255) bbase[nbuck] = e;   // safe duplicate
}

// ---------------- pass 1: multisplit into packed bucket runs ----------------
// packed edge = (dstLocal << 22) | src   (src < 2^22, dstLocal < 1024)
__global__ __launch_bounds__(256) void multisplit(const int* __restrict__ src,
        const int* __restrict__ dst, int* __restrict__ bcur,
        int* __restrict__ packed, int e, int nbuck) {
    __shared__ int cnt[MAXB], lbase[MAXB], wbase[MAXB], vcnt[MAXB], scanbuf[256];
    __shared__ int buf[CHUNK];
    const int t = threadIdx.x;
    const int e0 = blockIdx.x * CHUNK;
    const int m = min(CHUNK, e - e0);

    for (int i = t; i < nbuck; i += 256) cnt[i] = 0;
    __syncthreads();
    for (int i = t; i < m; i += 256) atomicAdd(&cnt[dst[e0 + i] >> BSH], 1);
    __syncthreads();
    // exclusive scan of cnt[0..nbuck) (nbuck <= 256)
    int v = (t < nbuck) ? cnt[t] : 0;
    scanbuf[t] = v;
    __syncthreads();
    for (int off = 1; off < 256; off <<= 1) {
        int u = (t >= off) ? scanbuf[t - off] : 0;
        __syncthreads();
        scanbuf[t] += u;
        __syncthreads();
    }
    int excl = scanbuf[t] - v;
    if (t < nbuck) {
        lbase[t] = excl;
        vcnt[t] = v;
        wbase[t] = v ? atomicAdd(&bcur[t], v) : 0;
        cnt[t] = excl;              // becomes local cursor
    }
    __syncthreads();
    for (int i = t; i < m; i += 256) {
        int d = dst[e0 + i], s = src[e0 + i];
        int b = d >> BSH;
        int p = atomicAdd(&cnt[b], 1);
        buf[p] = ((d & ((1 << BSH) - 1)) << 22) | s;
    }
    __syncthreads();
    // flush per-bucket runs coalesced
    int wv = t >> 6, ln = t & 63;
    for (int b = wv; b < nbuck; b += 4) {
        int c = vcnt[b], st = lbase[b], g = wbase[b];
        for (int i = ln; i < c; i += 64) packed[g + i] = buf[st + i];
    }
}

// ---------------- pass 2: per-bucket deg/roff/dinv/csr ----------------
__global__ __launch_bounds__(256) void bucket_build(const int* __restrict__ packed,
        const int* __restrict__ bbase, int* __restrict__ roff,
        float* __restrict__ dinv, int* __restrict__ csr, int n, int e_total) {
    __shared__ int deg[1 << BSH];
    __shared__ int cur[1 << BSH];
    __shared__ int wsum[4];
    const int t = threadIdx.x;
    const int b = blockIdx.x;
    const int nodeBase = b << BSH;
    const int nn = min(1 << BSH, n - nodeBase);
    const int e0 = bbase[b], e1 = bbase[b + 1];

    for (int i = t; i < (1 << BSH); i += 256) deg[i] = 0;
    __syncthreads();
    for (int i = e0 + t; i < e1; i += 256)
        atomicAdd(&deg[(unsigned)packed[i] >> 22], 1);
    __syncthreads();

    // block exclusive scan of deg[0..1024), 4 elems/thread
    const int i0 = t * 4;
    int d0 = deg[i0], d1 = deg[i0 + 1], d2 = deg[i0 + 2], d3 = deg[i0 + 3];
    int tsum = d0 + d1 + d2 + d3;
    int lane = t & 63, wv = t >> 6;
    int v = tsum;
    for (int off = 1; off < 64; off <<= 1) {
        int u = __shfl_up(v, off, 64);
        if (lane >= off) v += u;
    }
    if (lane == 63) wsum[wv] = v;
    __syncthreads();
    int woff = 0;
    for (int i = 0; i < wv; ++i) woff += wsum[i];
    int excl = v - tsum + woff;
    int p0 = excl, p1 = excl + d0, p2 = p1 + d1, p3 = p2 + d2;
    cur[i0] = p0; cur[i0 + 1] = p1; cur[i0 + 2] = p2; cur[i0 + 3] = p3;
#pragma unroll
    for (int j = 0; j < 4; ++j) {
        int li = i0 + j;
        if (li < nn) {
            int pp = (j == 0) ? p0 : (j == 1) ? p1 : (j == 2) ? p2 : p3;
            int dd = (j == 0) ? d0 : (j == 1) ? d1 : (j == 2) ? d2 : d3;
            roff[nodeBase + li] = e0 + pp;
            dinv[nodeBase + li] = rsqrtf((float)(dd + 1));
        }
    }
    if (b == 0 && t == 0) roff[n] = e_total;
    __syncthreads();

    // fill csr (block-local region [e0,e1): lines fill fully before eviction)
    for (int i = e0 + t; i < e1; i += 256) {
        unsigned pk = (unsigned)packed[i];
        int dl = pk >> 22;
        int s = pk & 0x3FFFFF;
        int slot = atomicAdd(&cur[dl], 1);
        csr[e0 + slot] = s;
    }
}

// ---------------- register-tiled GEMM: out[i][c] = dinv[i] * sum_k x[i][k]*W[k][c] ----
template<int C, int KSTAGE>
__global__ __launch_bounds__(256) void gemm_tiled(const float* __restrict__ x,
        const float* __restrict__ W, const float* __restrict__ dinv,
        float* __restrict__ out, int n)
{
    constexpr int CT = C / 16;                  // 8 for C=128, 4 for C=64
    __shared__ __align__(16) float lws[KSTAGE * C];
    __shared__ float lx[64][KD + 2];
    const int t = threadIdx.x;
    const int row0 = blockIdx.x * 64;

    for (int i = t; i < 64 * (KD / 4); i += 256) {
        int r = i >> 5, k4 = (i & 31) * 4;
        int row = row0 + r;
        float4 v = make_float4(0.f, 0.f, 0.f, 0.f);
        if (row < n) v = *reinterpret_cast<const float4*>(&x[(size_t)row * KD + k4]);
        lx[r][k4 + 0] = v.x; lx[r][k4 + 1] = v.y;
        lx[r][k4 + 2] = v.z; lx[r][k4 + 3] = v.w;
    }

    const int ty = t >> 4;
    const int tx = t & 15;
    const int r0 = ty * 4;
    const int cb = tx * CT;

    float acc[4][CT];
#pragma unroll
    for (int i = 0; i < 4; ++i)
#pragma unroll
        for (int j = 0; j < CT; ++j) acc[i][j] = 0.0f;

    for (int kt = 0; kt < KD / KSTAGE; ++kt) {
        __syncthreads();
        {
            const float4* W4 = reinterpret_cast<const float4*>(W + (size_t)kt * KSTAGE * C);
            float4* l4 = reinterpret_cast<float4*>(lws);
            for (int i = t; i < KSTAGE * C / 4; i += 256) l4[i] = W4[i];
        }
        __syncthreads();
        const int kb = kt * KSTAGE;
#pragma unroll 4
        for (int k = 0; k < KSTAGE; k += 2) {
            float2 xv[4];
#pragma unroll
            for (int i = 0; i < 4; ++i)
                xv[i] = *reinterpret_cast<const float2*>(&lx[r0 + i][kb + k]);
#pragma unroll
            for (int kk = 0; kk < 2; ++kk) {
#pragma unroll
                for (int j = 0; j < CT / 4; ++j) {
                    float4 wv = *reinterpret_cast<const float4*>(&lws[(k + kk) * C + cb + 4 * j]);
#pragma unroll
                    for (int i = 0; i < 4; ++i) {
                        float xs = kk ? xv[i].y : xv[i].x;
                        acc[i][4*j+0] += xs * wv.x;
                        acc[i][4*j+1] += xs * wv.y;
                        acc[i][4*j+2] += xs * wv.z;
                        acc[i][4*j+3] += xs * wv.w;
                    }
                }
            }
        }
    }

#pragma unroll
    for (int i = 0; i < 4; ++i) {
        int row = row0 + r0 + i;
        if (row < n) {
            float s = dinv[row];
#pragma unroll
            for (int j = 0; j < CT / 4; ++j) {
                float4 v = make_float4(acc[i][4*j+0]*s, acc[i][4*j+1]*s,
                                       acc[i][4*j+2]*s, acc[i][4*j+3]*s);
                *reinterpret_cast<float4*>(&out[(size_t)row * C + cb + 4*j]) = v;
            }
        }
    }
}

// ---------------- gather-aggregate: one wave per node (unchanged from R5) ------------
template<bool RELU>
__global__ __launch_bounds__(256) void gather128(const float* __restrict__ h,
        const int* __restrict__ roff, const int* __restrict__ csr,
        const float* __restrict__ dinv, const float* __restrict__ b,
        float* __restrict__ out, int n)
{
    int wid = (blockIdx.x * 256 + threadIdx.x) >> 6;
    int lane = threadIdx.x & 63;
    if (wid >= n) return;
    const float2* hl = (const float2*)h + lane;
    float2 acc = hl[(size_t)wid * 64];          // self loop
    float2 a1 = make_float2(0.f, 0.f);
    int e0 = roff[wid], e1 = roff[wid + 1];
    for (int base = e0; base < e1; base += 64) {
        int m = e1 - base; if (m > 64) m = 64;
        int idx = (lane < m) ? csr[base + lane] : 0;
        int j = 0;
        for (; j + 8 <= m; j += 8) {
            int u0 = __shfl(idx, j+0), u1 = __shfl(idx, j+1);
            int u2 = __shfl(idx, j+2), u3 = __shfl(idx, j+3);
            int u4 = __shfl(idx, j+4), u5 = __shfl(idx, j+5);
            int u6 = __shfl(idx, j+6), u7 = __shfl(idx, j+7);
            float2 t0 = hl[(size_t)u0 * 64];
            float2 t1 = hl[(size_t)u1 * 64];
            float2 t2 = hl[(size_t)u2 * 64];
            float2 t3 = hl[(size_t)u3 * 64];
            float2 t4 = hl[(size_t)u4 * 64];
            float2 t5 = hl[(size_t)u5 * 64];
            float2 t6 = hl[(size_t)u6 * 64];
            float2 t7 = hl[(size_t)u7 * 64];
            acc.x += t0.x + t1.x; acc.y += t0.y + t1.y;
            a1.x  += t2.x + t3.x; a1.y  += t2.y + t3.y;
            acc.x += t4.x + t5.x; acc.y += t4.y + t5.y;
            a1.x  += t6.x + t7.x; a1.y  += t6.y + t7.y;
        }
        for (; j < m; ++j) {
            int u = __shfl(idx, j);
            float2 t = hl[(size_t)u * 64];
            acc.x += t.x; acc.y += t.y;
        }
    }
    acc.x += a1.x; acc.y += a1.y;
    float s = dinv[wid];
    float2 bb = ((const float2*)b)[lane];
    acc.x = s * acc.x + bb.x;
    acc.y = s * acc.y + bb.y;
    if (RELU) { acc.x = fmaxf(acc.x, 0.f); acc.y = fmaxf(acc.y, 0.f); }
    ((float2*)out)[(size_t)wid * 64 + lane] = acc;
}

template<bool RELU>
__global__ __launch_bounds__(256) void gather64(const float* __restrict__ h,
        const int* __restrict__ roff, const int* __restrict__ csr,
        const float* __restrict__ dinv, const float* __restrict__ b,
        float* __restrict__ out, int n)
{
    int wid = (blockIdx.x * 256 + threadIdx.x) >> 6;
    int lane = threadIdx.x & 63;
    if (wid >= n) return;
    const float* hl = h + lane;
    float acc = hl[(size_t)wid * 64];           // self loop
    float a1 = 0.f;
    int e0 = roff[wid], e1 = roff[wid + 1];
    for (int base = e0; base < e1; base += 64) {
        int m = e1 - base; if (m > 64) m = 64;
        int idx = (lane < m) ? csr[base + lane] : 0;
        int j = 0;
        for (; j + 8 <= m; j += 8) {
            int u0 = __shfl(idx, j+0), u1 = __shfl(idx, j+1);
            int u2 = __shfl(idx, j+2), u3 = __shfl(idx, j+3);
            int u4 = __shfl(idx, j+4), u5 = __shfl(idx, j+5);
            int u6 = __shfl(idx, j+6), u7 = __shfl(idx, j+7);
            float t0 = hl[(size_t)u0 * 64];
            float t1 = hl[(size_t)u1 * 64];
            float t2 = hl[(size_t)u2 * 64];
            float t3 = hl[(size_t)u3 * 64];
            float t4 = hl[(size_t)u4 * 64];
            float t5 = hl[(size_t)u5 * 64];
            float t6 = hl[(size_t)u6 * 64];
            float t7 = hl[(size_t)u7 * 64];
            acc += t0 + t1; a1 += t2 + t3;
            acc += t4 + t5; a1 += t6 + t7;
        }
        for (; j < m; ++j) {
            int u = __shfl(idx, j);
            acc += hl[(size_t)u * 64];
        }
    }
    acc += a1;
    float v = dinv[wid] * acc + b[lane];
    if (RELU) v = fmaxf(v, 0.f);
    out[(size_t)wid * 64 + lane] = v;
}

extern "C" void kernel_launch(void* const* d_in, const int* in_sizes, int n_in,
                              void* d_out, int out_size, void* d_ws, size_t ws_size,
                              hipStream_t stream)
{
    const int* ei = (const int*)d_in[0];
    const int E = in_sizes[0] / 2;
    const float* emb = (const float*)d_in[1];
    const int N = in_sizes[1] / KD;
    const float* W1 = (const float*)d_in[2];
    const float* b1 = (const float*)d_in[3];
    const float* W2 = (const float*)d_in[4];
    const float* b2 = (const float*)d_in[5];
    const int* src = ei;        // edge_index[0]
    const int* dst = ei + E;    // edge_index[1]
    const int nbuck = (N + (1 << BSH) - 1) >> BSH;   // 98 for N=100000

    // ---- workspace layout ----
    char* p = (char*)d_ws;
    auto alloc = [&](size_t bytes) { char* q = p; p += (bytes + 255) & ~(size_t)255; return q; };
    float* h1     = (float*)alloc((size_t)N * 128 * sizeof(float)); // gemm1 out; reused as h2 [N*64]
    float* x2     = (float*)alloc((size_t)N * 128 * sizeof(float)); // layer-1 activations
    int*   csr    = (int*)  alloc((size_t)E * sizeof(int));
    int*   packed = (int*)  alloc((size_t)E * sizeof(int));
    int*   roff   = (int*)  alloc((size_t)(N + 1) * sizeof(int));
    float* dinv   = (float*)alloc((size_t)N * sizeof(float));
    int*   bcnt   = (int*)  alloc(MAXB * sizeof(int));
    int*   bbase  = (int*)  alloc((MAXB + 1) * sizeof(int));
    int*   bcur   = (int*)  alloc(MAXB * sizeof(int));
    float* h2     = h1;

    // ---- bucketed CSR build ----
    hipMemsetAsync(bcnt, 0, MAXB * sizeof(int), stream);
    bucket_count<<<256, 256, 0, stream>>>(dst, bcnt, E, nbuck);
    bucket_scan<<<1, 256, 0, stream>>>(bcnt, bbase, bcur, nbuck, E);
    multisplit<<<(E + CHUNK - 1) / CHUNK, 256, 0, stream>>>(src, dst, bcur, packed, E, nbuck);
    bucket_build<<<nbuck, 256, 0, stream>>>(packed, bbase, roff, dinv, csr, N, E);

    // ---- layer 1 ----
    gemm_tiled<128, 32><<<(N + 63) / 64, 256, 0, stream>>>(emb, W1, dinv, h1, N);
    gather128<true><<<(N + 3) / 4, 256, 0, stream>>>(h1, roff, csr, dinv, b1, x2, N);

    // ---- layer 2 ----
    gemm_tiled<64, 64><<<(N + 63) / 64, 256, 0, stream>>>(x2, W2, dinv, h2, N);
    gather64<false><<<(N + 3) / 4, 256, 0, stream>>>(h2, roff, csr, dinv, b2, (float*)d_out, N);
}

// Round 7
// 398.857 us; speedup vs baseline: 1.4765x; 1.1490x over previous
//
#include <hip/hip_runtime.h>
#include <hip/hip_bf16.h>
#include <stdint.h>

// GCN: out = Dinv (A+I) Dinv (X W) + b, two layers, relu between.
// N=100000, E=1600000, K=128, C1=128, C2=64. fp32 in/out (edge_index int32).
// R7: h1/h2 stored bf16 (gather is pure-BW: R6 measured 401MB fetch @3.9TB/s on
//     gather128). fp32 accumulate everywhere; x2 kept fp32 to bound error.
//     Bucketed CSR build from R6 (scatter locality: lines fill before eviction).

static constexpr int KD = 128;
static constexpr int BSH = 10;                 // nodes per bucket = 1024
static constexpr int MAXB = 256;               // max buckets supported
static constexpr int CHUNK = 8192;             // edges per multisplit block

__device__ __forceinline__ unsigned short f2bf(float f) {
    __hip_bfloat16 b = __float2bfloat16(f);    // RNE
    return *reinterpret_cast<unsigned short*>(&b);
}

// ---------------- pass 0: bucket histogram ----------------
__global__ __launch_bounds__(256) void bucket_count(const int* __restrict__ dst,
        int* __restrict__ bcnt, int e, int nbuck) {
    __shared__ int cnt[MAXB];
    const int t = threadIdx.x;
    for (int i = t; i < nbuck; i += 256) cnt[i] = 0;
    __syncthreads();
    int stride = gridDim.x * 256;
    for (int i = blockIdx.x * 256 + t; i < e; i += stride)
        atomicAdd(&cnt[dst[i] >> BSH], 1);
    __syncthreads();
    for (int i = t; i < nbuck; i += 256)
        if (cnt[i]) atomicAdd(&bcnt[i], cnt[i]);
}

// ---------------- scan buckets (1 block) ----------------
__global__ __launch_bounds__(256) void bucket_scan(const int* __restrict__ bcnt,
        int* __restrict__ bbase, int* __restrict__ bcur, int nbuck, int e) {
    __shared__ int buf[256];
    const int t = threadIdx.x;
    int v = (t < nbuck) ? bcnt[t] : 0;
    buf[t] = v;
    __syncthreads();
    for (int off = 1; off < 256; off <<= 1) {
        int u = (t >= off) ? buf[t - off] : 0;
        __syncthreads();
        buf[t] += u;
        __syncthreads();
    }
    int excl = buf[t] - v;
    if (t < nbuck) { bbase[t] = excl; bcur[t] = excl; }
    if (t == 0) bbase[nbuck] = e;
}

// ---------------- pass 1: multisplit into packed bucket runs ----------------
// packed edge = (dstLocal << 22) | src   (src < 2^22, dstLocal < 1024)
__global__ __launch_bounds__(256) void multisplit(const int* __restrict__ src,
        const int* __restrict__ dst, int* __restrict__ bcur,
        int* __restrict__ packed, int e, int nbuck) {
    __shared__ int cnt[MAXB], lbase[MAXB], wbase[MAXB], vcnt[MAXB], scanbuf[256];
    __shared__ int buf[CHUNK];
    const int t = threadIdx.x;
    const int e0 = blockIdx.x * CHUNK;
    const int m = min(CHUNK, e - e0);

    for (int i = t; i < nbuck; i += 256) cnt[i] = 0;
    __syncthreads();
    for (int i = t; i < m; i += 256) atomicAdd(&cnt[dst[e0 + i] >> BSH], 1);
    __syncthreads();
    int v = (t < nbuck) ? cnt[t] : 0;
    scanbuf[t] = v;
    __syncthreads();
    for (int off = 1; off < 256; off <<= 1) {
        int u = (t >= off) ? scanbuf[t - off] : 0;
        __syncthreads();
        scanbuf[t] += u;
        __syncthreads();
    }
    int excl = scanbuf[t] - v;
    if (t < nbuck) {
        lbase[t] = excl;
        vcnt[t] = v;
        wbase[t] = v ? atomicAdd(&bcur[t], v) : 0;
        cnt[t] = excl;              // becomes local cursor
    }
    __syncthreads();
    for (int i = t; i < m; i += 256) {
        int d = dst[e0 + i], s = src[e0 + i];
        int b = d >> BSH;
        int p = atomicAdd(&cnt[b], 1);
        buf[p] = ((d & ((1 << BSH) - 1)) << 22) | s;
    }
    __syncthreads();
    int wv = t >> 6, ln = t & 63;
    for (int b = wv; b < nbuck; b += 4) {
        int c = vcnt[b], st = lbase[b], g = wbase[b];
        for (int i = ln; i < c; i += 64) packed[g + i] = buf[st + i];
    }
}

// ---------------- pass 2: per-bucket deg/roff/dinv/csr ----------------
__global__ __launch_bounds__(256) void bucket_build(const int* __restrict__ packed,
        const int* __restrict__ bbase, int* __restrict__ roff,
        float* __restrict__ dinv, int* __restrict__ csr, int n, int e_total) {
    __shared__ int deg[1 << BSH];
    __shared__ int cur[1 << BSH];
    __shared__ int wsum[4];
    const int t = threadIdx.x;
    const int b = blockIdx.x;
    const int nodeBase = b << BSH;
    const int nn = min(1 << BSH, n - nodeBase);
    const int e0 = bbase[b], e1 = bbase[b + 1];

    for (int i = t; i < (1 << BSH); i += 256) deg[i] = 0;
    __syncthreads();
    for (int i = e0 + t; i < e1; i += 256)
        atomicAdd(&deg[(unsigned)packed[i] >> 22], 1);
    __syncthreads();

    const int i0 = t * 4;
    int d0 = deg[i0], d1 = deg[i0 + 1], d2 = deg[i0 + 2], d3 = deg[i0 + 3];
    int tsum = d0 + d1 + d2 + d3;
    int lane = t & 63, wv = t >> 6;
    int v = tsum;
    for (int off = 1; off < 64; off <<= 1) {
        int u = __shfl_up(v, off, 64);
        if (lane >= off) v += u;
    }
    if (lane == 63) wsum[wv] = v;
    __syncthreads();
    int woff = 0;
    for (int i = 0; i < wv; ++i) woff += wsum[i];
    int excl = v - tsum + woff;
    int p0 = excl, p1 = excl + d0, p2 = p1 + d1, p3 = p2 + d2;
    cur[i0] = p0; cur[i0 + 1] = p1; cur[i0 + 2] = p2; cur[i0 + 3] = p3;
#pragma unroll
    for (int j = 0; j < 4; ++j) {
        int li = i0 + j;
        if (li < nn) {
            int pp = (j == 0) ? p0 : (j == 1) ? p1 : (j == 2) ? p2 : p3;
            int dd = (j == 0) ? d0 : (j == 1) ? d1 : (j == 2) ? d2 : d3;
            roff[nodeBase + li] = e0 + pp;
            dinv[nodeBase + li] = rsqrtf((float)(dd + 1));
        }
    }
    if (b == 0 && t == 0) roff[n] = e_total;
    __syncthreads();

    for (int i = e0 + t; i < e1; i += 256) {
        unsigned pk = (unsigned)packed[i];
        int dl = pk >> 22;
        int s = pk & 0x3FFFFF;
        int slot = atomicAdd(&cur[dl], 1);
        csr[e0 + slot] = s;
    }
}

// ---------------- register-tiled GEMM, bf16 output ----------------
// out_bf[i][c] = bf16( dinv[i] * sum_k x[i][k]*W[k][c] )
template<int C, int KSTAGE>
__global__ __launch_bounds__(256) void gemm_tiled_bf(const float* __restrict__ x,
        const float* __restrict__ W, const float* __restrict__ dinv,
        unsigned short* __restrict__ out, int n)
{
    constexpr int CT = C / 16;                  // 8 for C=128, 4 for C=64
    __shared__ __align__(16) float lws[KSTAGE * C];
    __shared__ float lx[64][KD + 2];
    const int t = threadIdx.x;
    const int row0 = blockIdx.x * 64;

    for (int i = t; i < 64 * (KD / 4); i += 256) {
        int r = i >> 5, k4 = (i & 31) * 4;
        int row = row0 + r;
        float4 v = make_float4(0.f, 0.f, 0.f, 0.f);
        if (row < n) v = *reinterpret_cast<const float4*>(&x[(size_t)row * KD + k4]);
        lx[r][k4 + 0] = v.x; lx[r][k4 + 1] = v.y;
        lx[r][k4 + 2] = v.z; lx[r][k4 + 3] = v.w;
    }

    const int ty = t >> 4;
    const int tx = t & 15;
    const int r0 = ty * 4;
    const int cb = tx * CT;

    float acc[4][CT];
#pragma unroll
    for (int i = 0; i < 4; ++i)
#pragma unroll
        for (int j = 0; j < CT; ++j) acc[i][j] = 0.0f;

    for (int kt = 0; kt < KD / KSTAGE; ++kt) {
        __syncthreads();
        {
            const float4* W4 = reinterpret_cast<const float4*>(W + (size_t)kt * KSTAGE * C);
            float4* l4 = reinterpret_cast<float4*>(lws);
            for (int i = t; i < KSTAGE * C / 4; i += 256) l4[i] = W4[i];
        }
        __syncthreads();
        const int kb = kt * KSTAGE;
#pragma unroll 4
        for (int k = 0; k < KSTAGE; k += 2) {
            float2 xv[4];
#pragma unroll
            for (int i = 0; i < 4; ++i)
                xv[i] = *reinterpret_cast<const float2*>(&lx[r0 + i][kb + k]);
#pragma unroll
            for (int kk = 0; kk < 2; ++kk) {
#pragma unroll
                for (int j = 0; j < CT / 4; ++j) {
                    float4 wv = *reinterpret_cast<const float4*>(&lws[(k + kk) * C + cb + 4 * j]);
#pragma unroll
                    for (int i = 0; i < 4; ++i) {
                        float xs = kk ? xv[i].y : xv[i].x;
                        acc[i][4*j+0] += xs * wv.x;
                        acc[i][4*j+1] += xs * wv.y;
                        acc[i][4*j+2] += xs * wv.z;
                        acc[i][4*j+3] += xs * wv.w;
                    }
                }
            }
        }
    }

#pragma unroll
    for (int i = 0; i < 4; ++i) {
        int row = row0 + r0 + i;
        if (row < n) {
            float s = dinv[row];
            unsigned pk[CT / 2];
#pragma unroll
            for (int j = 0; j < CT / 2; ++j) {
                unsigned lo = f2bf(acc[i][2*j+0] * s);
                unsigned hi = f2bf(acc[i][2*j+1] * s);
                pk[j] = lo | (hi << 16);
            }
            unsigned* dstp = reinterpret_cast<unsigned*>(&out[(size_t)row * C + cb]);
#pragma unroll
            for (int j = 0; j < CT / 2; ++j) dstp[j] = pk[j];
        }
    }
}

// ---------------- gather-aggregate from bf16 h, one wave per node ----------------
// h: bf16 [n, 128]; lane handles 2 cols via one uint load (4B -> 256B/row/wave).
template<bool RELU>
__global__ __launch_bounds__(256) void gather128(const unsigned* __restrict__ h32,
        const int* __restrict__ roff, const int* __restrict__ csr,
        const float* __restrict__ dinv, const float* __restrict__ b,
        float* __restrict__ out, int n)
{
    int wid = (blockIdx.x * 256 + threadIdx.x) >> 6;
    int lane = threadIdx.x & 63;
    if (wid >= n) return;
    const unsigned* hl = h32 + lane;
    unsigned sv = hl[(size_t)wid * 64];
    float ax = __uint_as_float(sv << 16);
    float ay = __uint_as_float(sv & 0xffff0000u);
    float bx = 0.f, by = 0.f;
    int e0 = roff[wid], e1 = roff[wid + 1];
    for (int base = e0; base < e1; base += 64) {
        int m = e1 - base; if (m > 64) m = 64;
        int idx = (lane < m) ? csr[base + lane] : 0;
        int j = 0;
        for (; j + 8 <= m; j += 8) {
            int u0 = __shfl(idx, j+0), u1 = __shfl(idx, j+1);
            int u2 = __shfl(idx, j+2), u3 = __shfl(idx, j+3);
            int u4 = __shfl(idx, j+4), u5 = __shfl(idx, j+5);
            int u6 = __shfl(idx, j+6), u7 = __shfl(idx, j+7);
            unsigned v0 = hl[(size_t)u0 * 64];
            unsigned v1 = hl[(size_t)u1 * 64];
            unsigned v2 = hl[(size_t)u2 * 64];
            unsigned v3 = hl[(size_t)u3 * 64];
            unsigned v4 = hl[(size_t)u4 * 64];
            unsigned v5 = hl[(size_t)u5 * 64];
            unsigned v6 = hl[(size_t)u6 * 64];
            unsigned v7 = hl[(size_t)u7 * 64];
            ax += __uint_as_float(v0 << 16) + __uint_as_float(v1 << 16);
            ay += __uint_as_float(v0 & 0xffff0000u) + __uint_as_float(v1 & 0xffff0000u);
            bx += __uint_as_float(v2 << 16) + __uint_as_float(v3 << 16);
            by += __uint_as_float(v2 & 0xffff0000u) + __uint_as_float(v3 & 0xffff0000u);
            ax += __uint_as_float(v4 << 16) + __uint_as_float(v5 << 16);
            ay += __uint_as_float(v4 & 0xffff0000u) + __uint_as_float(v5 & 0xffff0000u);
            bx += __uint_as_float(v6 << 16) + __uint_as_float(v7 << 16);
            by += __uint_as_float(v6 & 0xffff0000u) + __uint_as_float(v7 & 0xffff0000u);
        }
        for (; j < m; ++j) {
            int u = __shfl(idx, j);
            unsigned v = hl[(size_t)u * 64];
            ax += __uint_as_float(v << 16);
            ay += __uint_as_float(v & 0xffff0000u);
        }
    }
    ax += bx; ay += by;
    float s = dinv[wid];
    float2 bb = ((const float2*)b)[lane];
    ax = s * ax + bb.x;
    ay = s * ay + bb.y;
    if (RELU) { ax = fmaxf(ax, 0.f); ay = fmaxf(ay, 0.f); }
    ((float2*)out)[(size_t)wid * 64 + lane] = make_float2(ax, ay);
}

// h: bf16 [n, 64]; lane handles 1 col via ushort load (128B/row/wave).
template<bool RELU>
__global__ __launch_bounds__(256) void gather64(const unsigned short* __restrict__ h,
        const int* __restrict__ roff, const int* __restrict__ csr,
        const float* __restrict__ dinv, const float* __restrict__ b,
        float* __restrict__ out, int n)
{
    int wid = (blockIdx.x * 256 + threadIdx.x) >> 6;
    int lane = threadIdx.x & 63;
    if (wid >= n) return;
    const unsigned short* hl = h + lane;
    float acc = __uint_as_float((unsigned)hl[(size_t)wid * 64] << 16);
    float a1 = 0.f;
    int e0 = roff[wid], e1 = roff[wid + 1];
    for (int base = e0; base < e1; base += 64) {
        int m = e1 - base; if (m > 64) m = 64;
        int idx = (lane < m) ? csr[base + lane] : 0;
        int j = 0;
        for (; j + 8 <= m; j += 8) {
            int u0 = __shfl(idx, j+0), u1 = __shfl(idx, j+1);
            int u2 = __shfl(idx, j+2), u3 = __shfl(idx, j+3);
            int u4 = __shfl(idx, j+4), u5 = __shfl(idx, j+5);
            int u6 = __shfl(idx, j+6), u7 = __shfl(idx, j+7);
            float t0 = __uint_as_float((unsigned)hl[(size_t)u0 * 64] << 16);
            float t1 = __uint_as_float((unsigned)hl[(size_t)u1 * 64] << 16);
            float t2 = __uint_as_float((unsigned)hl[(size_t)u2 * 64] << 16);
            float t3 = __uint_as_float((unsigned)hl[(size_t)u3 * 64] << 16);
            float t4 = __uint_as_float((unsigned)hl[(size_t)u4 * 64] << 16);
            float t5 = __uint_as_float((unsigned)hl[(size_t)u5 * 64] << 16);
            float t6 = __uint_as_float((unsigned)hl[(size_t)u6 * 64] << 16);
            float t7 = __uint_as_float((unsigned)hl[(size_t)u7 * 64] << 16);
            acc += t0 + t1; a1 += t2 + t3;
            acc += t4 + t5; a1 += t6 + t7;
        }
        for (; j < m; ++j) {
            int u = __shfl(idx, j);
            acc += __uint_as_float((unsigned)hl[(size_t)u * 64] << 16);
        }
    }
    acc += a1;
    float v = dinv[wid] * acc + b[lane];
    if (RELU) v = fmaxf(v, 0.f);
    out[(size_t)wid * 64 + lane] = v;
}

extern "C" void kernel_launch(void* const* d_in, const int* in_sizes, int n_in,
                              void* d_out, int out_size, void* d_ws, size_t ws_size,
                              hipStream_t stream)
{
    const int* ei = (const int*)d_in[0];
    const int E = in_sizes[0] / 2;
    const float* emb = (const float*)d_in[1];
    const int N = in_sizes[1] / KD;
    const float* W1 = (const float*)d_in[2];
    const float* b1 = (const float*)d_in[3];
    const float* W2 = (const float*)d_in[4];
    const float* b2 = (const float*)d_in[5];
    const int* src = ei;        // edge_index[0]
    const int* dst = ei + E;    // edge_index[1]
    const int nbuck = (N + (1 << BSH) - 1) >> BSH;   // 98 for N=100000

    // ---- workspace layout ----
    char* p = (char*)d_ws;
    auto alloc = [&](size_t bytes) { char* q = p; p += (bytes + 255) & ~(size_t)255; return q; };
    unsigned short* h1 = (unsigned short*)alloc((size_t)N * 128 * sizeof(unsigned short)); // bf16
    float* x2     = (float*)alloc((size_t)N * 128 * sizeof(float)); // layer-1 activations fp32
    int*   csr    = (int*)  alloc((size_t)E * sizeof(int));
    int*   packed = (int*)  alloc((size_t)E * sizeof(int));
    int*   roff   = (int*)  alloc((size_t)(N + 1) * sizeof(int));
    float* dinv   = (float*)alloc((size_t)N * sizeof(float));
    int*   bcnt   = (int*)  alloc(MAXB * sizeof(int));
    int*   bbase  = (int*)  alloc((MAXB + 1) * sizeof(int));
    int*   bcur   = (int*)  alloc(MAXB * sizeof(int));
    unsigned short* h2 = h1;                        // bf16 [N,64], h1 dead after gather128

    // ---- bucketed CSR build ----
    hipMemsetAsync(bcnt, 0, MAXB * sizeof(int), stream);
    bucket_count<<<256, 256, 0, stream>>>(dst, bcnt, E, nbuck);
    bucket_scan<<<1, 256, 0, stream>>>(bcnt, bbase, bcur, nbuck, E);
    multisplit<<<(E + CHUNK - 1) / CHUNK, 256, 0, stream>>>(src, dst, bcur, packed, E, nbuck);
    bucket_build<<<nbuck, 256, 0, stream>>>(packed, bbase, roff, dinv, csr, N, E);

    // ---- layer 1 ----
    gemm_tiled_bf<128, 32><<<(N + 63) / 64, 256, 0, stream>>>(emb, W1, dinv, h1, N);
    gather128<true><<<(N + 3) / 4, 256, 0, stream>>>((const unsigned*)h1, roff, csr, dinv, b1, x2, N);

    // ---- layer 2 ----
    gemm_tiled_bf<64, 64><<<(N + 63) / 64, 256, 0, stream>>>(x2, W2, dinv, h2, N);
    gather64<false><<<(N + 3) / 4, 256, 0, stream>>>(h2, roff, csr, dinv, b2, (float*)d_out, N);
}

// Round 8
// 347.061 us; speedup vs baseline: 1.6968x; 1.1492x over previous
//
#include <hip/hip_runtime.h>
#include <hip/hip_bf16.h>
#include <stdint.h>

// GCN: out = Dinv (A+I) Dinv (X W) + b, two layers, relu between.
// N=100000, E=1600000, K=128, C1=128, C2=64. fp32 in/out (edge_index int32).
// R8: GEMMs -> MFMA v_mfma_f32_16x16x32_bf16 (fp32 acc). R7 measured gemm_tiled_bf
//     at 78us: 6.8M LDS bank conflicts (cb=tx*8 4-way alias) + 24% occupancy;
//     memory floor is ~15us. W pre-transposed to bf16 Wt[n][k]; A-tile LDS pad +8
//     shorts (2-way alias only = free). h1/h2 bf16 (R7), bucketed CSR build (R6).

static constexpr int KD = 128;
static constexpr int BSH = 10;                 // nodes per bucket = 1024
static constexpr int MAXB = 256;               // max buckets supported
static constexpr int CHUNK = 8192;             // edges per multisplit block

typedef short bf16x8 __attribute__((ext_vector_type(8)));
typedef float f32x4  __attribute__((ext_vector_type(4)));

__device__ __forceinline__ unsigned short f2bf(float f) {
    __hip_bfloat16 b = __float2bfloat16(f);    // RNE
    return *reinterpret_cast<unsigned short*>(&b);
}

// ---------------- pass 0: bucket histogram ----------------
__global__ __launch_bounds__(256) void bucket_count(const int* __restrict__ dst,
        int* __restrict__ bcnt, int e, int nbuck) {
    __shared__ int cnt[MAXB];
    const int t = threadIdx.x;
    for (int i = t; i < nbuck; i += 256) cnt[i] = 0;
    __syncthreads();
    int stride = gridDim.x * 256;
    for (int i = blockIdx.x * 256 + t; i < e; i += stride)
        atomicAdd(&cnt[dst[i] >> BSH], 1);
    __syncthreads();
    for (int i = t; i < nbuck; i += 256)
        if (cnt[i]) atomicAdd(&bcnt[i], cnt[i]);
}

// ---------------- scan buckets (1 block) ----------------
__global__ __launch_bounds__(256) void bucket_scan(const int* __restrict__ bcnt,
        int* __restrict__ bbase, int* __restrict__ bcur, int nbuck, int e) {
    __shared__ int buf[256];
    const int t = threadIdx.x;
    int v = (t < nbuck) ? bcnt[t] : 0;
    buf[t] = v;
    __syncthreads();
    for (int off = 1; off < 256; off <<= 1) {
        int u = (t >= off) ? buf[t - off] : 0;
        __syncthreads();
        buf[t] += u;
        __syncthreads();
    }
    int excl = buf[t] - v;
    if (t < nbuck) { bbase[t] = excl; bcur[t] = excl; }
    if (t == 0) bbase[nbuck] = e;
}

// ---------------- pass 1: multisplit into packed bucket runs ----------------
__global__ __launch_bounds__(256) void multisplit(const int* __restrict__ src,
        const int* __restrict__ dst, int* __restrict__ bcur,
        int* __restrict__ packed, int e, int nbuck) {
    __shared__ int cnt[MAXB], lbase[MAXB], wbase[MAXB], vcnt[MAXB], scanbuf[256];
    __shared__ int buf[CHUNK];
    const int t = threadIdx.x;
    const int e0 = blockIdx.x * CHUNK;
    const int m = min(CHUNK, e - e0);

    for (int i = t; i < nbuck; i += 256) cnt[i] = 0;
    __syncthreads();
    for (int i = t; i < m; i += 256) atomicAdd(&cnt[dst[e0 + i] >> BSH], 1);
    __syncthreads();
    int v = (t < nbuck) ? cnt[t] : 0;
    scanbuf[t] = v;
    __syncthreads();
    for (int off = 1; off < 256; off <<= 1) {
        int u = (t >= off) ? scanbuf[t - off] : 0;
        __syncthreads();
        scanbuf[t] += u;
        __syncthreads();
    }
    int excl = scanbuf[t] - v;
    if (t < nbuck) {
        lbase[t] = excl;
        vcnt[t] = v;
        wbase[t] = v ? atomicAdd(&bcur[t], v) : 0;
        cnt[t] = excl;              // becomes local cursor
    }
    __syncthreads();
    for (int i = t; i < m; i += 256) {
        int d = dst[e0 + i], s = src[e0 + i];
        int b = d >> BSH;
        int p = atomicAdd(&cnt[b], 1);
        buf[p] = ((d & ((1 << BSH) - 1)) << 22) | s;
    }
    __syncthreads();
    int wv = t >> 6, ln = t & 63;
    for (int b = wv; b < nbuck; b += 4) {
        int c = vcnt[b], st = lbase[b], g = wbase[b];
        for (int i = ln; i < c; i += 64) packed[g + i] = buf[st + i];
    }
}

// ---------------- pass 2: per-bucket deg/roff/dinv/csr ----------------
__global__ __launch_bounds__(256) void bucket_build(const int* __restrict__ packed,
        const int* __restrict__ bbase, int* __restrict__ roff,
        float* __restrict__ dinv, int* __restrict__ csr, int n, int e_total) {
    __shared__ int deg[1 << BSH];
    __shared__ int cur[1 << BSH];
    __shared__ int wsum[4];
    const int t = threadIdx.x;
    const int b = blockIdx.x;
    const int nodeBase = b << BSH;
    const int nn = min(1 << BSH, n - nodeBase);
    const int e0 = bbase[b], e1 = bbase[b + 1];

    for (int i = t; i < (1 << BSH); i += 256) deg[i] = 0;
    __syncthreads();
    for (int i = e0 + t; i < e1; i += 256)
        atomicAdd(&deg[(unsigned)packed[i] >> 22], 1);
    __syncthreads();

    const int i0 = t * 4;
    int d0 = deg[i0], d1 = deg[i0 + 1], d2 = deg[i0 + 2], d3 = deg[i0 + 3];
    int tsum = d0 + d1 + d2 + d3;
    int lane = t & 63, wv = t >> 6;
    int v = tsum;
    for (int off = 1; off < 64; off <<= 1) {
        int u = __shfl_up(v, off, 64);
        if (lane >= off) v += u;
    }
    if (lane == 63) wsum[wv] = v;
    __syncthreads();
    int woff = 0;
    for (int i = 0; i < wv; ++i) woff += wsum[i];
    int excl = v - tsum + woff;
    int p0 = excl, p1 = excl + d0, p2 = p1 + d1, p3 = p2 + d2;
    cur[i0] = p0; cur[i0 + 1] = p1; cur[i0 + 2] = p2; cur[i0 + 3] = p3;
#pragma unroll
    for (int j = 0; j < 4; ++j) {
        int li = i0 + j;
        if (li < nn) {
            int pp = (j == 0) ? p0 : (j == 1) ? p1 : (j == 2) ? p2 : p3;
            int dd = (j == 0) ? d0 : (j == 1) ? d1 : (j == 2) ? d2 : d3;
            roff[nodeBase + li] = e0 + pp;
            dinv[nodeBase + li] = rsqrtf((float)(dd + 1));
        }
    }
    if (b == 0 && t == 0) roff[n] = e_total;
    __syncthreads();

    for (int i = e0 + t; i < e1; i += 256) {
        unsigned pk = (unsigned)packed[i];
        int dl = pk >> 22;
        int s = pk & 0x3FFFFF;
        int slot = atomicAdd(&cur[dl], 1);
        csr[e0 + slot] = s;
    }
}

// ---------------- W transpose to bf16: Wt[n][k] = bf16(W[k][n]) ----------------
__global__ __launch_bounds__(256) void transposeW(const float* __restrict__ W1,
        const float* __restrict__ W2, unsigned short* __restrict__ Wt1,
        unsigned short* __restrict__ Wt2) {
    int t = blockIdx.x * 256 + threadIdx.x;
    if (t < 128 * 128) {
        int k = t >> 7, nn = t & 127;
        Wt1[nn * 128 + k] = f2bf(W1[t]);
    } else if (t < 128 * 128 + 128 * 64) {
        int i = t - 128 * 128;
        int k = i >> 6, nn = i & 63;
        Wt2[nn * 128 + k] = f2bf(W2[i]);
    }
}

// ---------------- MFMA GEMM: out_bf[i][c] = bf16(dinv[i] * sum_k x[i][k]*W[k][c]) ----
// 64 rows x C cols per block, 4 waves; wave w = rows w*16..+15, C/16 acc tiles.
// A: x fp32 -> bf16 in LDS, row pad +8 shorts (2-way bank alias only).
// B: Wt[n][k] bf16 staged per k-half, row pad +8.
template<int C>
__global__ __launch_bounds__(256) void gemm_mfma(const float* __restrict__ x,
        const unsigned short* __restrict__ Wt, const float* __restrict__ dinv,
        unsigned short* __restrict__ out, int n)
{
    constexpr int KP = KD + 8;                 // 136 shorts = 272B row stride
    constexpr int WP = 64 + 8;                 // 72 shorts = 144B row stride
    __shared__ __align__(16) unsigned short xt[64 * KP];
    __shared__ __align__(16) unsigned short lw[C * WP];
    const int t = threadIdx.x;
    const int w = t >> 6, lane = t & 63;
    const int quad = lane >> 4, l16 = lane & 15;
    const int row0 = blockIdx.x * 64;

    // stage x tile: coalesced float4 reads, bf16 convert, 8B LDS writes
    for (int i = t; i < 64 * 32; i += 256) {
        int r = i >> 5, c4 = (i & 31) * 4;
        int row = row0 + r;
        float4 v = make_float4(0.f, 0.f, 0.f, 0.f);
        if (row < n) v = *reinterpret_cast<const float4*>(&x[(size_t)row * KD + c4]);
        ushort4 pk;
        pk.x = f2bf(v.x); pk.y = f2bf(v.y); pk.z = f2bf(v.z); pk.w = f2bf(v.w);
        *reinterpret_cast<ushort4*>(&xt[r * KP + c4]) = pk;
    }

    f32x4 acc[C / 16];
#pragma unroll
    for (int i = 0; i < C / 16; ++i) acc[i] = (f32x4)(0.f);

    for (int h = 0; h < 2; ++h) {
        __syncthreads();   // h=0: covers xt writes; h=1: waits for lw readers
        for (int i = t; i < C * 16; i += 256) {       // 8B chunks, 16 per Wt row
            int nr = i >> 4, j = (i & 15) * 4;
            *reinterpret_cast<ushort4*>(&lw[nr * WP + j]) =
                *reinterpret_cast<const ushort4*>(&Wt[nr * KD + h * 64 + j]);
        }
        __syncthreads();
#pragma unroll
        for (int kt = 0; kt < 2; ++kt) {
            // A frag: A[m=l16][k=quad*8+j]
            bf16x8 af = *reinterpret_cast<const bf16x8*>(
                &xt[(w * 16 + l16) * KP + h * 64 + kt * 32 + quad * 8]);
#pragma unroll
            for (int ct = 0; ct < C / 16; ++ct) {
                // B frag: B[k=quad*8+j][n=l16] from Wt[n][k]
                bf16x8 bfr = *reinterpret_cast<const bf16x8*>(
                    &lw[(ct * 16 + l16) * WP + kt * 32 + quad * 8]);
                acc[ct] = __builtin_amdgcn_mfma_f32_16x16x32_bf16(af, bfr, acc[ct], 0, 0, 0);
            }
        }
    }

    // epilogue: D layout col = ct*16 + l16, row = quad*4 + j
#pragma unroll
    for (int j = 0; j < 4; ++j) {
        int row = row0 + w * 16 + quad * 4 + j;
        if (row < n) {
            float s = dinv[row];
#pragma unroll
            for (int ct = 0; ct < C / 16; ++ct)
                out[(size_t)row * C + ct * 16 + l16] = f2bf(acc[ct][j] * s);
        }
    }
}

// ---------------- gather-aggregate from bf16 h, one wave per node ----------------
template<bool RELU>
__global__ __launch_bounds__(256) void gather128(const unsigned* __restrict__ h32,
        const int* __restrict__ roff, const int* __restrict__ csr,
        const float* __restrict__ dinv, const float* __restrict__ b,
        float* __restrict__ out, int n)
{
    int wid = (blockIdx.x * 256 + threadIdx.x) >> 6;
    int lane = threadIdx.x & 63;
    if (wid >= n) return;
    const unsigned* hl = h32 + lane;
    unsigned sv = hl[(size_t)wid * 64];
    float ax = __uint_as_float(sv << 16);
    float ay = __uint_as_float(sv & 0xffff0000u);
    float bx = 0.f, by = 0.f;
    int e0 = roff[wid], e1 = roff[wid + 1];
    for (int base = e0; base < e1; base += 64) {
        int m = e1 - base; if (m > 64) m = 64;
        int idx = (lane < m) ? csr[base + lane] : 0;
        int j = 0;
        for (; j + 8 <= m; j += 8) {
            int u0 = __shfl(idx, j+0), u1 = __shfl(idx, j+1);
            int u2 = __shfl(idx, j+2), u3 = __shfl(idx, j+3);
            int u4 = __shfl(idx, j+4), u5 = __shfl(idx, j+5);
            int u6 = __shfl(idx, j+6), u7 = __shfl(idx, j+7);
            unsigned v0 = hl[(size_t)u0 * 64];
            unsigned v1 = hl[(size_t)u1 * 64];
            unsigned v2 = hl[(size_t)u2 * 64];
            unsigned v3 = hl[(size_t)u3 * 64];
            unsigned v4 = hl[(size_t)u4 * 64];
            unsigned v5 = hl[(size_t)u5 * 64];
            unsigned v6 = hl[(size_t)u6 * 64];
            unsigned v7 = hl[(size_t)u7 * 64];
            ax += __uint_as_float(v0 << 16) + __uint_as_float(v1 << 16);
            ay += __uint_as_float(v0 & 0xffff0000u) + __uint_as_float(v1 & 0xffff0000u);
            bx += __uint_as_float(v2 << 16) + __uint_as_float(v3 << 16);
            by += __uint_as_float(v2 & 0xffff0000u) + __uint_as_float(v3 & 0xffff0000u);
            ax += __uint_as_float(v4 << 16) + __uint_as_float(v5 << 16);
            ay += __uint_as_float(v4 & 0xffff0000u) + __uint_as_float(v5 & 0xffff0000u);
            bx += __uint_as_float(v6 << 16) + __uint_as_float(v7 << 16);
            by += __uint_as_float(v6 & 0xffff0000u) + __uint_as_float(v7 & 0xffff0000u);
        }
        for (; j < m; ++j) {
            int u = __shfl(idx, j);
            unsigned v = hl[(size_t)u * 64];
            ax += __uint_as_float(v << 16);
            ay += __uint_as_float(v & 0xffff0000u);
        }
    }
    ax += bx; ay += by;
    float s = dinv[wid];
    float2 bb = ((const float2*)b)[lane];
    ax = s * ax + bb.x;
    ay = s * ay + bb.y;
    if (RELU) { ax = fmaxf(ax, 0.f); ay = fmaxf(ay, 0.f); }
    ((float2*)out)[(size_t)wid * 64 + lane] = make_float2(ax, ay);
}

template<bool RELU>
__global__ __launch_bounds__(256) void gather64(const unsigned short* __restrict__ h,
        const int* __restrict__ roff, const int* __restrict__ csr,
        const float* __restrict__ dinv, const float* __restrict__ b,
        float* __restrict__ out, int n)
{
    int wid = (blockIdx.x * 256 + threadIdx.x) >> 6;
    int lane = threadIdx.x & 63;
    if (wid >= n) return;
    const unsigned short* hl = h + lane;
    float acc = __uint_as_float((unsigned)hl[(size_t)wid * 64] << 16);
    float a1 = 0.f;
    int e0 = roff[wid], e1 = roff[wid + 1];
    for (int base = e0; base < e1; base += 64) {
        int m = e1 - base; if (m > 64) m = 64;
        int idx = (lane < m) ? csr[base + lane] : 0;
        int j = 0;
        for (; j + 8 <= m; j += 8) {
            int u0 = __shfl(idx, j+0), u1 = __shfl(idx, j+1);
            int u2 = __shfl(idx, j+2), u3 = __shfl(idx, j+3);
            int u4 = __shfl(idx, j+4), u5 = __shfl(idx, j+5);
            int u6 = __shfl(idx, j+6), u7 = __shfl(idx, j+7);
            float t0 = __uint_as_float((unsigned)hl[(size_t)u0 * 64] << 16);
            float t1 = __uint_as_float((unsigned)hl[(size_t)u1 * 64] << 16);
            float t2 = __uint_as_float((unsigned)hl[(size_t)u2 * 64] << 16);
            float t3 = __uint_as_float((unsigned)hl[(size_t)u3 * 64] << 16);
            float t4 = __uint_as_float((unsigned)hl[(size_t)u4 * 64] << 16);
            float t5 = __uint_as_float((unsigned)hl[(size_t)u5 * 64] << 16);
            float t6 = __uint_as_float((unsigned)hl[(size_t)u6 * 64] << 16);
            float t7 = __uint_as_float((unsigned)hl[(size_t)u7 * 64] << 16);
            acc += t0 + t1; a1 += t2 + t3;
            acc += t4 + t5; a1 += t6 + t7;
        }
        for (; j < m; ++j) {
            int u = __shfl(idx, j);
            acc += __uint_as_float((unsigned)hl[(size_t)u * 64] << 16);
        }
    }
    acc += a1;
    float v = dinv[wid] * acc + b[lane];
    if (RELU) v = fmaxf(v, 0.f);
    out[(size_t)wid * 64 + lane] = v;
}

extern "C" void kernel_launch(void* const* d_in, const int* in_sizes, int n_in,
                              void* d_out, int out_size, void* d_ws, size_t ws_size,
                              hipStream_t stream)
{
    const int* ei = (const int*)d_in[0];
    const int E = in_sizes[0] / 2;
    const float* emb = (const float*)d_in[1];
    const int N = in_sizes[1] / KD;
    const float* W1 = (const float*)d_in[2];
    const float* b1 = (const float*)d_in[3];
    const float* W2 = (const float*)d_in[4];
    const float* b2 = (const float*)d_in[5];
    const int* src = ei;        // edge_index[0]
    const int* dst = ei + E;    // edge_index[1]
    const int nbuck = (N + (1 << BSH) - 1) >> BSH;   // 98 for N=100000

    // ---- workspace layout ----
    char* p = (char*)d_ws;
    auto alloc = [&](size_t bytes) { char* q = p; p += (bytes + 255) & ~(size_t)255; return q; };
    unsigned short* h1 = (unsigned short*)alloc((size_t)N * 128 * sizeof(unsigned short)); // bf16
    float* x2     = (float*)alloc((size_t)N * 128 * sizeof(float)); // layer-1 activations fp32
    int*   csr    = (int*)  alloc((size_t)E * sizeof(int));
    int*   packed = (int*)  alloc((size_t)E * sizeof(int));
    int*   roff   = (int*)  alloc((size_t)(N + 1) * sizeof(int));
    float* dinv   = (float*)alloc((size_t)N * sizeof(float));
    int*   bcnt   = (int*)  alloc(MAXB * sizeof(int));
    int*   bbase  = (int*)  alloc((MAXB + 1) * sizeof(int));
    int*   bcur   = (int*)  alloc(MAXB * sizeof(int));
    unsigned short* Wt1 = (unsigned short*)alloc(128 * 128 * sizeof(unsigned short));
    unsigned short* Wt2 = (unsigned short*)alloc(64 * 128 * sizeof(unsigned short));
    unsigned short* h2 = h1;                        // bf16 [N,64], h1 dead after gather128

    // ---- bucketed CSR build + weight transpose ----
    hipMemsetAsync(bcnt, 0, MAXB * sizeof(int), stream);
    transposeW<<<96, 256, 0, stream>>>(W1, W2, Wt1, Wt2);
    bucket_count<<<256, 256, 0, stream>>>(dst, bcnt, E, nbuck);
    bucket_scan<<<1, 256, 0, stream>>>(bcnt, bbase, bcur, nbuck, E);
    multisplit<<<(E + CHUNK - 1) / CHUNK, 256, 0, stream>>>(src, dst, bcur, packed, E, nbuck);
    bucket_build<<<nbuck, 256, 0, stream>>>(packed, bbase, roff, dinv, csr, N, E);

    // ---- layer 1 ----
    gemm_mfma<128><<<(N + 63) / 64, 256, 0, stream>>>(emb, Wt1, dinv, h1, N);
    gather128<true><<<(N + 3) / 4, 256, 0, stream>>>((const unsigned*)h1, roff, csr, dinv, b1, x2, N);

    // ---- layer 2 ----
    gemm_mfma<64><<<(N + 63) / 64, 256, 0, stream>>>(x2, Wt2, dinv, h2, N);
    gather64<false><<<(N + 3) / 4, 256, 0, stream>>>(h2, roff, csr, dinv, b2, (float*)d_out, N);
}

// Round 9
// 323.064 us; speedup vs baseline: 1.8229x; 1.0743x over previous
//
#include <hip/hip_runtime.h>
#include <hip/hip_bf16.h>
#include <stdint.h>

// GCN: out = Dinv (A+I) Dinv (X W) + b, two layers, relu between.
// N=100000, E=1600000, K=128, C1=128, C2=64. fp32 in/out (edge_index int32).
// R9: gather128 FETCH=192MB == 7.5x h1 => at XCD-replication floor; attack the rest:
//   - x2 stored bf16 (bit-identical to gemm2's own rounding): -50MB write, -25MB read
//   - fixed-capacity buckets (CAP=24576): kills memset+bucket_count+bucket_scan;
//     gathers use deg[] so inter-bucket holes in csr are harmless
//   - gather64 v2: half-wave per edge (uint loads, __shfl_xor combine) = 2 edges/instr
//   MFMA GEMMs (R8), bf16 h (R7), bucket-local csr fill (R6).

static constexpr int KD = 128;
static constexpr int BSH = 10;                 // nodes per bucket = 1024
static constexpr int MAXB = 256;               // max buckets supported
static constexpr int CHUNK = 8192;             // edges per multisplit block
static constexpr int CAP = 24576;              // bucket capacity (E/98 ~ 16.3k + huge margin)

typedef short bf16x8 __attribute__((ext_vector_type(8)));
typedef float f32x4  __attribute__((ext_vector_type(4)));

__device__ __forceinline__ unsigned short f2bf(float f) {
    __hip_bfloat16 b = __float2bfloat16(f);    // RNE
    return *reinterpret_cast<unsigned short*>(&b);
}
__device__ __forceinline__ float bflo(unsigned v) { return __uint_as_float(v << 16); }
__device__ __forceinline__ float bfhi(unsigned v) { return __uint_as_float(v & 0xffff0000u); }

// ---------------- init: W transpose to bf16 + bucket cursor init ----------------
__global__ __launch_bounds__(256) void init_misc(const float* __restrict__ W1,
        const float* __restrict__ W2, unsigned short* __restrict__ Wt1,
        unsigned short* __restrict__ Wt2, int* __restrict__ bcur, int nbuck) {
    int t = blockIdx.x * 256 + threadIdx.x;
    if (t < 128 * 128) {
        int k = t >> 7, nn = t & 127;
        Wt1[nn * 128 + k] = f2bf(W1[t]);
    } else if (t < 128 * 128 + 128 * 64) {
        int i = t - 128 * 128;
        int k = i >> 6, nn = i & 63;
        Wt2[nn * 128 + k] = f2bf(W2[i]);
    } else if (t < 128 * 128 + 128 * 64 + MAXB) {
        int b = t - (128 * 128 + 128 * 64);
        bcur[b] = b * CAP;
    }
}

// ---------------- multisplit into fixed-capacity bucket regions ----------------
// packed edge = (dstLocal << 22) | src   (src < 2^22, dstLocal < 1024)
__global__ __launch_bounds__(256) void multisplit(const int* __restrict__ src,
        const int* __restrict__ dst, int* __restrict__ bcur,
        int* __restrict__ packed, int e, int nbuck) {
    __shared__ int cnt[MAXB], lbase[MAXB], wbase[MAXB], vcnt[MAXB], scanbuf[256];
    __shared__ int buf[CHUNK];
    const int t = threadIdx.x;
    const int e0 = blockIdx.x * CHUNK;
    const int m = min(CHUNK, e - e0);

    for (int i = t; i < nbuck; i += 256) cnt[i] = 0;
    __syncthreads();
    for (int i = t; i < m; i += 256) atomicAdd(&cnt[dst[e0 + i] >> BSH], 1);
    __syncthreads();
    int v = (t < nbuck) ? cnt[t] : 0;
    scanbuf[t] = v;
    __syncthreads();
    for (int off = 1; off < 256; off <<= 1) {
        int u = (t >= off) ? scanbuf[t - off] : 0;
        __syncthreads();
        scanbuf[t] += u;
        __syncthreads();
    }
    int excl = scanbuf[t] - v;
    if (t < nbuck) {
        lbase[t] = excl;
        vcnt[t] = v;
        wbase[t] = v ? atomicAdd(&bcur[t], v) : 0;
        cnt[t] = excl;              // becomes local cursor
    }
    __syncthreads();
    for (int i = t; i < m; i += 256) {
        int d = dst[e0 + i], s = src[e0 + i];
        int b = d >> BSH;
        int p = atomicAdd(&cnt[b], 1);
        buf[p] = ((d & ((1 << BSH) - 1)) << 22) | s;
    }
    __syncthreads();
    int wv = t >> 6, ln = t & 63;
    for (int b = wv; b < nbuck; b += 4) {
        int c = vcnt[b], st = lbase[b], g = wbase[b];
        int end = min(c, (b + 1) * CAP - g);    // overflow guard (never expected)
        for (int i = ln; i < end; i += 64) packed[g + i] = buf[st + i];
    }
}

// ---------------- per-bucket deg/roff/dinv/csr ----------------
__global__ __launch_bounds__(256) void bucket_build(const int* __restrict__ packed,
        const int* __restrict__ bcur, int* __restrict__ roff, int* __restrict__ degN,
        float* __restrict__ dinv, int* __restrict__ csr, int n) {
    __shared__ int deg[1 << BSH];
    __shared__ int cur[1 << BSH];
    __shared__ int wsum[4];
    const int t = threadIdx.x;
    const int b = blockIdx.x;
    const int nodeBase = b << BSH;
    const int nn = min(1 << BSH, n - nodeBase);
    const int e0 = b * CAP, e1 = bcur[b];

    for (int i = t; i < (1 << BSH); i += 256) deg[i] = 0;
    __syncthreads();
    for (int i = e0 + t; i < e1; i += 256)
        atomicAdd(&deg[(unsigned)packed[i] >> 22], 1);
    __syncthreads();

    const int i0 = t * 4;
    int d0 = deg[i0], d1 = deg[i0 + 1], d2 = deg[i0 + 2], d3 = deg[i0 + 3];
    int tsum = d0 + d1 + d2 + d3;
    int lane = t & 63, wv = t >> 6;
    int v = tsum;
    for (int off = 1; off < 64; off <<= 1) {
        int u = __shfl_up(v, off, 64);
        if (lane >= off) v += u;
    }
    if (lane == 63) wsum[wv] = v;
    __syncthreads();
    int woff = 0;
    for (int i = 0; i < wv; ++i) woff += wsum[i];
    int excl = v - tsum + woff;
    int p0 = excl, p1 = excl + d0, p2 = p1 + d1, p3 = p2 + d2;
    cur[i0] = p0; cur[i0 + 1] = p1; cur[i0 + 2] = p2; cur[i0 + 3] = p3;
#pragma unroll
    for (int j = 0; j < 4; ++j) {
        int li = i0 + j;
        if (li < nn) {
            int pp = (j == 0) ? p0 : (j == 1) ? p1 : (j == 2) ? p2 : p3;
            int dd = (j == 0) ? d0 : (j == 1) ? d1 : (j == 2) ? d2 : d3;
            roff[nodeBase + li] = e0 + pp;
            degN[nodeBase + li] = dd;
            dinv[nodeBase + li] = rsqrtf((float)(dd + 1));
        }
    }
    __syncthreads();

    for (int i = e0 + t; i < e1; i += 256) {
        unsigned pk = (unsigned)packed[i];
        int dl = pk >> 22;
        int s = pk & 0x3FFFFF;
        int slot = atomicAdd(&cur[dl], 1);
        csr[e0 + slot] = s;
    }
}

// ---------------- MFMA GEMM: out_bf[i][c] = bf16(dinv[i] * sum_k x[i][k]*W[k][c]) ----
// 64 rows x C cols per block, 4 waves. XBF: input already bf16.
template<int C, bool XBF>
__global__ __launch_bounds__(256) void gemm_mfma(const void* __restrict__ xv,
        const unsigned short* __restrict__ Wt, const float* __restrict__ dinv,
        unsigned short* __restrict__ out, int n)
{
    constexpr int KP = KD + 8;                 // 136 shorts = 272B row stride
    constexpr int WP = 64 + 8;                 // 72 shorts = 144B row stride
    __shared__ __align__(16) unsigned short xt[64 * KP];
    __shared__ __align__(16) unsigned short lw[C * WP];
    const int t = threadIdx.x;
    const int w = t >> 6, lane = t & 63;
    const int quad = lane >> 4, l16 = lane & 15;
    const int row0 = blockIdx.x * 64;

    // stage x tile (4 cols per iter)
    for (int i = t; i < 64 * 32; i += 256) {
        int r = i >> 5, c4 = (i & 31) * 4;
        int row = row0 + r;
        ushort4 pk = make_ushort4(0, 0, 0, 0);
        if (row < n) {
            if constexpr (XBF) {
                pk = *reinterpret_cast<const ushort4*>(
                    &((const unsigned short*)xv)[(size_t)row * KD + c4]);
            } else {
                float4 v = *reinterpret_cast<const float4*>(
                    &((const float*)xv)[(size_t)row * KD + c4]);
                pk.x = f2bf(v.x); pk.y = f2bf(v.y); pk.z = f2bf(v.z); pk.w = f2bf(v.w);
            }
        }
        *reinterpret_cast<ushort4*>(&xt[r * KP + c4]) = pk;
    }

    f32x4 acc[C / 16];
#pragma unroll
    for (int i = 0; i < C / 16; ++i) acc[i] = (f32x4)(0.f);

    for (int h = 0; h < 2; ++h) {
        __syncthreads();   // h=0: covers xt writes; h=1: waits for lw readers
        for (int i = t; i < C * 16; i += 256) {       // 8B chunks, 16 per Wt half-row
            int nr = i >> 4, j = (i & 15) * 4;
            *reinterpret_cast<ushort4*>(&lw[nr * WP + j]) =
                *reinterpret_cast<const ushort4*>(&Wt[nr * KD + h * 64 + j]);
        }
        __syncthreads();
#pragma unroll
        for (int kt = 0; kt < 2; ++kt) {
            bf16x8 af = *reinterpret_cast<const bf16x8*>(
                &xt[(w * 16 + l16) * KP + h * 64 + kt * 32 + quad * 8]);
#pragma unroll
            for (int ct = 0; ct < C / 16; ++ct) {
                bf16x8 bfr = *reinterpret_cast<const bf16x8*>(
                    &lw[(ct * 16 + l16) * WP + kt * 32 + quad * 8]);
                acc[ct] = __builtin_amdgcn_mfma_f32_16x16x32_bf16(af, bfr, acc[ct], 0, 0, 0);
            }
        }
    }

    // epilogue: D layout col = ct*16 + l16, row = quad*4 + j
#pragma unroll
    for (int j = 0; j < 4; ++j) {
        int row = row0 + w * 16 + quad * 4 + j;
        if (row < n) {
            float s = dinv[row];
#pragma unroll
            for (int ct = 0; ct < C / 16; ++ct)
                out[(size_t)row * C + ct * 16 + l16] = f2bf(acc[ct][j] * s);
        }
    }
}

// ---------------- gather128: one wave per node, bf16 in, bf16 out (x2) ----------
__global__ __launch_bounds__(256) void gather128(const unsigned* __restrict__ h32,
        const int* __restrict__ roff, const int* __restrict__ degN,
        const int* __restrict__ csr, const float* __restrict__ dinv,
        const float* __restrict__ b, unsigned* __restrict__ out, int n)
{
    int wid = (blockIdx.x * 256 + threadIdx.x) >> 6;
    int lane = threadIdx.x & 63;
    if (wid >= n) return;
    const unsigned* hl = h32 + lane;
    unsigned sv = hl[(size_t)wid * 64];
    float ax = bflo(sv), ay = bfhi(sv);
    float bx = 0.f, by = 0.f;
    int e0 = roff[wid], e1 = e0 + degN[wid];
    for (int base = e0; base < e1; base += 64) {
        int m = e1 - base; if (m > 64) m = 64;
        int idx = (lane < m) ? csr[base + lane] : 0;
        int j = 0;
        for (; j + 8 <= m; j += 8) {
            int u0 = __shfl(idx, j+0), u1 = __shfl(idx, j+1);
            int u2 = __shfl(idx, j+2), u3 = __shfl(idx, j+3);
            int u4 = __shfl(idx, j+4), u5 = __shfl(idx, j+5);
            int u6 = __shfl(idx, j+6), u7 = __shfl(idx, j+7);
            unsigned v0 = hl[(size_t)u0 * 64];
            unsigned v1 = hl[(size_t)u1 * 64];
            unsigned v2 = hl[(size_t)u2 * 64];
            unsigned v3 = hl[(size_t)u3 * 64];
            unsigned v4 = hl[(size_t)u4 * 64];
            unsigned v5 = hl[(size_t)u5 * 64];
            unsigned v6 = hl[(size_t)u6 * 64];
            unsigned v7 = hl[(size_t)u7 * 64];
            ax += bflo(v0) + bflo(v1); ay += bfhi(v0) + bfhi(v1);
            bx += bflo(v2) + bflo(v3); by += bfhi(v2) + bfhi(v3);
            ax += bflo(v4) + bflo(v5); ay += bfhi(v4) + bfhi(v5);
            bx += bflo(v6) + bflo(v7); by += bfhi(v6) + bfhi(v7);
        }
        for (; j < m; ++j) {
            int u = __shfl(idx, j);
            unsigned v = hl[(size_t)u * 64];
            ax += bflo(v); ay += bfhi(v);
        }
    }
    ax += bx; ay += by;
    float s = dinv[wid];
    float2 bb = ((const float2*)b)[lane];
    ax = fmaxf(s * ax + bb.x, 0.f);            // relu
    ay = fmaxf(s * ay + bb.y, 0.f);
    out[(size_t)wid * 64 + lane] = (unsigned)f2bf(ax) | ((unsigned)f2bf(ay) << 16);
}

// ---------------- gather64 v2: half-wave per edge (2 edges per wave-instr) ------
// h: bf16 [n,64] viewed as uint [n,32]; lane covers col pair cp=lane&31 of edge
// subset half=lane>>5; halves combined via shfl_xor(32) at the end.
__global__ __launch_bounds__(256) void gather64(const unsigned* __restrict__ h32,
        const int* __restrict__ roff, const int* __restrict__ degN,
        const int* __restrict__ csr, const float* __restrict__ dinv,
        const float* __restrict__ b, float* __restrict__ out, int n)
{
    int wid = (blockIdx.x * 256 + threadIdx.x) >> 6;
    int lane = threadIdx.x & 63;
    if (wid >= n) return;
    const int half = lane >> 5, cp = lane & 31;
    const unsigned* hl = h32 + cp;
    float ax = 0.f, ay = 0.f, bx = 0.f, by = 0.f;
    int e0 = roff[wid], e1 = e0 + degN[wid];
    for (int base = e0; base < e1; base += 64) {
        int m = e1 - base; if (m > 64) m = 64;
        int idx = (lane < m) ? csr[base + lane] : 0;
        int j = 0;
        for (; j + 8 <= m; j += 8) {           // this half takes j+half, j+2+half, ...
            int u0 = __shfl(idx, j + 0 + half);
            int u1 = __shfl(idx, j + 2 + half);
            int u2 = __shfl(idx, j + 4 + half);
            int u3 = __shfl(idx, j + 6 + half);
            unsigned v0 = hl[(size_t)u0 * 32];
            unsigned v1 = hl[(size_t)u1 * 32];
            unsigned v2 = hl[(size_t)u2 * 32];
            unsigned v3 = hl[(size_t)u3 * 32];
            ax += bflo(v0) + bflo(v1); ay += bfhi(v0) + bfhi(v1);
            bx += bflo(v2) + bflo(v3); by += bfhi(v2) + bfhi(v3);
        }
        for (; j + 2 <= m; j += 2) {
            int u = __shfl(idx, j + half);
            unsigned v = hl[(size_t)u * 32];
            ax += bflo(v); ay += bfhi(v);
        }
        if (j < m) {                            // single leftover edge -> half 0 only
            int u = __shfl(idx, j);
            if (half == 0) {
                unsigned v = hl[(size_t)u * 32];
                ax += bflo(v); ay += bfhi(v);
            }
        }
    }
    ax += bx; ay += by;
    ax += __shfl_xor(ax, 32, 64);              // combine halves (same col pair)
    ay += __shfl_xor(ay, 32, 64);
    unsigned sv = hl[(size_t)wid * 32];        // self loop (once, post-combine)
    ax += bflo(sv); ay += bfhi(sv);
    if (half == 0) {
        float s = dinv[wid];
        float2 bb = ((const float2*)b)[cp];
        ((float2*)out)[(size_t)wid * 32 + cp] =
            make_float2(s * ax + bb.x, s * ay + bb.y);
    }
}

extern "C" void kernel_launch(void* const* d_in, const int* in_sizes, int n_in,
                              void* d_out, int out_size, void* d_ws, size_t ws_size,
                              hipStream_t stream)
{
    const int* ei = (const int*)d_in[0];
    const int E = in_sizes[0] / 2;
    const float* emb = (const float*)d_in[1];
    const int N = in_sizes[1] / KD;
    const float* W1 = (const float*)d_in[2];
    const float* b1 = (const float*)d_in[3];
    const float* W2 = (const float*)d_in[4];
    const float* b2 = (const float*)d_in[5];
    const int* src = ei;        // edge_index[0]
    const int* dst = ei + E;    // edge_index[1]
    const int nbuck = (N + (1 << BSH) - 1) >> BSH;   // 98 for N=100000

    // ---- workspace layout ----
    char* p = (char*)d_ws;
    auto alloc = [&](size_t bytes) { char* q = p; p += (bytes + 255) & ~(size_t)255; return q; };
    unsigned short* h1 = (unsigned short*)alloc((size_t)N * 128 * sizeof(unsigned short)); // bf16
    unsigned short* x2 = (unsigned short*)alloc((size_t)N * 128 * sizeof(unsigned short)); // bf16
    int*   csr    = (int*)  alloc((size_t)nbuck * CAP * sizeof(int));
    int*   packed = (int*)  alloc((size_t)nbuck * CAP * sizeof(int));
    int*   roff   = (int*)  alloc((size_t)N * sizeof(int));
    int*   degN   = (int*)  alloc((size_t)N * sizeof(int));
    float* dinv   = (float*)alloc((size_t)N * sizeof(float));
    int*   bcur   = (int*)  alloc(MAXB * sizeof(int));
    unsigned short* Wt1 = (unsigned short*)alloc(128 * 128 * sizeof(unsigned short));
    unsigned short* Wt2 = (unsigned short*)alloc(64 * 128 * sizeof(unsigned short));
    unsigned short* h2 = h1;                        // bf16 [N,64], h1 dead after gather128

    // ---- CSR build (fixed-capacity buckets; no count/scan pass) ----
    init_misc<<<97, 256, 0, stream>>>(W1, W2, Wt1, Wt2, bcur, nbuck);
    multisplit<<<(E + CHUNK - 1) / CHUNK, 256, 0, stream>>>(src, dst, bcur, packed, E, nbuck);
    bucket_build<<<nbuck, 256, 0, stream>>>(packed, bcur, roff, degN, dinv, csr, N);

    // ---- layer 1 ----
    gemm_mfma<128, false><<<(N + 63) / 64, 256, 0, stream>>>(emb, Wt1, dinv, h1, N);
    gather128<<<(N + 3) / 4, 256, 0, stream>>>((const unsigned*)h1, roff, degN, csr,
                                               dinv, b1, (unsigned*)x2, N);

    // ---- layer 2 ----
    gemm_mfma<64, true><<<(N + 63) / 64, 256, 0, stream>>>(x2, Wt2, dinv, h2, N);
    gather64<<<(N + 3) / 4, 256, 0, stream>>>((const unsigned*)h2, roff, degN, csr,
                                              dinv, b2, (float*)d_out, N);
}